// Round 5
// baseline (1735.728 us; speedup 1.0000x reference)
//
#include <hip/hip_runtime.h>

// ImageMLP: y = softmax( actquant(x) @ ternquant(W)^T )
// x: [1024, 76800] f32, W: [8, 76800] f32, out: [1024, 8] f32
//
// Math: sx = 127/clip(rowmax,EPS), q_i = clip(rint(x_i*sx),-128,127) (int),
//       sw = 1/clip(mean|W|,EPS),  t_i = clip(rint(w_i*sw),-1,1) (ternary),
//   y[b][o] = (sum_i q_i * t_oi) * clip(rowmax,EPS) * clip(mean|W|,EPS) / 127
// q*t sums are integer-valued, |sum| < 2^24 -> exact in f32.
//
// v2 (resubmit; rounds 2-4 were infra failures): single HBM pass over x.
// Each 768-thread block holds a full row in registers (25 float4/thread),
// computes rowmax, then quant+dot from regs while prefetching the next row
// into the freed registers. Ternary codes stored transposed [f][8] so each
// element's 8 weights are 2 uint4 loads.

constexpr int B_ROWS  = 1024;
constexpr int I_ELEMS = 76800;       // 3*160*160
constexpr int I_F4    = 19200;       // float4s per row
constexpr int O_OUT   = 8;
constexpr int W_N     = O_OUT * I_ELEMS;  // 614400
constexpr int W_F4    = W_N / 4;          // 153600
constexpr float EPS   = 1e-5f;

constexpr int TPB = 768;             // threads per block (12 waves)
constexpr int F4T = 25;              // float4 per thread: 768*25 = 19200
constexpr int RPB = 4;               // rows per block -> grid = 256

// ---------------------------------------------------------------- W |.| sum
__global__ __launch_bounds__(256) void k_wabs_sum(const float* __restrict__ W,
                                                  double* __restrict__ wsum) {
  int tid = blockIdx.x * blockDim.x + threadIdx.x;
  int stride = gridDim.x * blockDim.x;
  float s = 0.f;
  for (int f = tid; f < W_F4; f += stride) {
    float4 v = reinterpret_cast<const float4*>(W)[f];
    s += fabsf(v.x) + fabsf(v.y) + fabsf(v.z) + fabsf(v.w);
  }
  double d = (double)s;
  #pragma unroll
  for (int off = 32; off; off >>= 1) d += __shfl_xor(d, off);
  __shared__ double lds[4];
  int lane = threadIdx.x & 63;
  int wv   = threadIdx.x >> 6;
  if (lane == 0) lds[wv] = d;
  __syncthreads();
  if (threadIdx.x == 0) atomicAdd(wsum, lds[0] + lds[1] + lds[2] + lds[3]);
}

// ------------------------------------- pack ternary W, TRANSPOSED [f][o]
// cT[f*8 + o] = dword whose byte e = (int8)t[o][4f+e]
__global__ __launch_bounds__(256) void k_pack(const float* __restrict__ W,
                                              const double* __restrict__ wsum,
                                              unsigned int* __restrict__ cT) {
  int tid = blockIdx.x * blockDim.x + threadIdx.x;
  if (tid >= W_F4) return;
  float meanc = fmaxf((float)(*wsum * (1.0 / (double)W_N)), EPS);
  float sw = 1.f / meanc;
  float4 v = reinterpret_cast<const float4*>(W)[tid];
  int b0 = (int)fminf(fmaxf(rintf(v.x * sw), -1.f), 1.f);
  int b1 = (int)fminf(fmaxf(rintf(v.y * sw), -1.f), 1.f);
  int b2 = (int)fminf(fmaxf(rintf(v.z * sw), -1.f), 1.f);
  int b3 = (int)fminf(fmaxf(rintf(v.w * sw), -1.f), 1.f);
  unsigned packed = (unsigned)(b0 & 0xff)        | ((unsigned)(b1 & 0xff) << 8) |
                    ((unsigned)(b2 & 0xff) << 16) | ((unsigned)(b3 & 0xff) << 24);
  int o = tid / I_F4;          // 0..7
  int f = tid - o * I_F4;      // 0..19199
  cT[(size_t)f * 8 + o] = packed;
}

// ----------------------------------------------------------------- fused main
__global__ __launch_bounds__(TPB) void k_main(const float* __restrict__ X,
                                              const unsigned int* __restrict__ cT,
                                              const double* __restrict__ wsum,
                                              float* __restrict__ out) {
  __shared__ float red[12];
  __shared__ float racc[12][8];
  const int t    = threadIdx.x;
  const int lane = t & 63;
  const int wv   = t >> 6;
  const float meanc = fmaxf((float)(*wsum * (1.0 / (double)W_N)), EPS);
  const int row0 = blockIdx.x * RPB;

  float4 d[F4T];
  {
    const float4* xr = reinterpret_cast<const float4*>(X) + (size_t)row0 * I_F4;
    #pragma unroll
    for (int j = 0; j < F4T; ++j) d[j] = xr[t + j * TPB];
  }

  #pragma unroll 1
  for (int r = 0; r < RPB; ++r) {
    // ---- rowmax from registers (loads complete here)
    float m = 0.f;
    #pragma unroll
    for (int j = 0; j < F4T; ++j) {
      float4 v = d[j];
      m = fmaxf(m, fmaxf(fmaxf(fabsf(v.x), fabsf(v.y)),
                         fmaxf(fabsf(v.z), fabsf(v.w))));
    }
    #pragma unroll
    for (int off = 32; off; off >>= 1) m = fmaxf(m, __shfl_xor(m, off));
    if (lane == 0) red[wv] = m;
    __syncthreads();
    float rowmax = red[0];
    #pragma unroll
    for (int i = 1; i < 12; ++i) rowmax = fmaxf(rowmax, red[i]);
    const float maxc = fmaxf(rowmax, EPS);
    const float sx = 127.f / maxc;

    // ---- quantize + ternary dot from registers; prefetch next row
    float acc[8];
    #pragma unroll
    for (int o = 0; o < O_OUT; ++o) acc[o] = 0.f;

    const bool pre = (r + 1 < RPB);
    // clamp so no OOB address is formed even speculatively
    const int nrow = pre ? (row0 + r + 1) : (row0 + r);
    const float4* xn = reinterpret_cast<const float4*>(X) + (size_t)nrow * I_F4;

    #pragma unroll
    for (int j = 0; j < F4T; ++j) {
      const int f = t + j * TPB;
      float4 v = d[j];
      if (pre) d[j] = xn[f];                 // uniform branch; frees regs
      float q0 = fminf(fmaxf(rintf(v.x * sx), -128.f), 127.f);
      float q1 = fminf(fmaxf(rintf(v.y * sx), -128.f), 127.f);
      float q2 = fminf(fmaxf(rintf(v.z * sx), -128.f), 127.f);
      float q3 = fminf(fmaxf(rintf(v.w * sx), -128.f), 127.f);
      const uint4* cp = reinterpret_cast<const uint4*>(cT + ((size_t)f << 3));
      uint4 c0 = cp[0];                      // o = 0..3
      uint4 c1 = cp[1];                      // o = 4..7
      unsigned cw;
      cw = c0.x; acc[0] += q0 * (float)((int)(cw << 24) >> 24) +
                           q1 * (float)((int)(cw << 16) >> 24) +
                           q2 * (float)((int)(cw <<  8) >> 24) +
                           q3 * (float)((int)cw >> 24);
      cw = c0.y; acc[1] += q0 * (float)((int)(cw << 24) >> 24) +
                           q1 * (float)((int)(cw << 16) >> 24) +
                           q2 * (float)((int)(cw <<  8) >> 24) +
                           q3 * (float)((int)cw >> 24);
      cw = c0.z; acc[2] += q0 * (float)((int)(cw << 24) >> 24) +
                           q1 * (float)((int)(cw << 16) >> 24) +
                           q2 * (float)((int)(cw <<  8) >> 24) +
                           q3 * (float)((int)cw >> 24);
      cw = c0.w; acc[3] += q0 * (float)((int)(cw << 24) >> 24) +
                           q1 * (float)((int)(cw << 16) >> 24) +
                           q2 * (float)((int)(cw <<  8) >> 24) +
                           q3 * (float)((int)cw >> 24);
      cw = c1.x; acc[4] += q0 * (float)((int)(cw << 24) >> 24) +
                           q1 * (float)((int)(cw << 16) >> 24) +
                           q2 * (float)((int)(cw <<  8) >> 24) +
                           q3 * (float)((int)cw >> 24);
      cw = c1.y; acc[5] += q0 * (float)((int)(cw << 24) >> 24) +
                           q1 * (float)((int)(cw << 16) >> 24) +
                           q2 * (float)((int)(cw <<  8) >> 24) +
                           q3 * (float)((int)cw >> 24);
      cw = c1.z; acc[6] += q0 * (float)((int)(cw << 24) >> 24) +
                           q1 * (float)((int)(cw << 16) >> 24) +
                           q2 * (float)((int)(cw <<  8) >> 24) +
                           q3 * (float)((int)cw >> 24);
      cw = c1.w; acc[7] += q0 * (float)((int)(cw << 24) >> 24) +
                           q1 * (float)((int)(cw << 16) >> 24) +
                           q2 * (float)((int)(cw <<  8) >> 24) +
                           q3 * (float)((int)cw >> 24);
    }

    // ---- reduce 8 sums over 12 waves (integer-valued floats: exact)
    #pragma unroll
    for (int o = 0; o < O_OUT; ++o) {
      float a = acc[o];
      #pragma unroll
      for (int off = 32; off; off >>= 1) a += __shfl_xor(a, off);
      if (lane == 0) racc[wv][o] = a;
    }
    __syncthreads();

    if (t == 0) {
      const float fin = maxc * meanc * (1.f / 127.f);
      float y[8];
      #pragma unroll
      for (int o = 0; o < O_OUT; ++o) {
        float s = 0.f;
        #pragma unroll
        for (int w = 0; w < 12; ++w) s += racc[w][o];
        y[o] = s * fin;
      }
      float mx = y[0];
      #pragma unroll
      for (int o = 1; o < O_OUT; ++o) mx = fmaxf(mx, y[o]);
      float e[8], s = 0.f;
      #pragma unroll
      for (int o = 0; o < O_OUT; ++o) { e[o] = expf(y[o] - mx); s += e[o]; }
      float inv = 1.f / s;
      #pragma unroll
      for (int o = 0; o < O_OUT; ++o) out[(row0 + r) * O_OUT + o] = e[o] * inv;
    }
    // no trailing barrier needed: next racc write happens only after the
    // next row's __syncthreads(), which t0 reaches after the softmax.
  }
}

// ------------------------------------------------------------------ launcher
extern "C" void kernel_launch(void* const* d_in, const int* in_sizes, int n_in,
                              void* d_out, int out_size, void* d_ws, size_t ws_size,
                              hipStream_t stream) {
  const float* X = (const float*)d_in[0];
  const float* W = (const float*)d_in[1];
  float* out = (float*)d_out;

  double* wsum = (double*)d_ws;                              // 8 bytes
  unsigned int* cT = (unsigned int*)((char*)d_ws + 64);      // 614400 bytes

  hipMemsetAsync(d_ws, 0, 8, stream);                        // zero wsum
  k_wabs_sum<<<256, 256, 0, stream>>>(W, wsum);
  k_pack<<<(W_F4 + 255) / 256, 256, 0, stream>>>(W, wsum, cT);
  k_main<<<B_ROWS / RPB, TPB, 0, stream>>>(X, cT, wsum, out);
}